// Round 1
// baseline (380.729 us; speedup 1.0000x reference)
//
#include <hip/hip_runtime.h>
#include <math.h>

// Masked-mean BCE-with-logits:
//   bce = max(x,0) - x*t + log1p(exp(-|x|)); out = sum(bce*m)/max(sum(m),1)
//
// R1: same-address double atomics serialize -> block partials.
// R2: libm log1pf ~250 VALU inst/elem -> HW __expf/__logf softplus.
// R3-R5: three structures converged ~2.9 TB/s -> looked like a ceiling.
// R6: NONTEMPORAL loads broke it (L2-allocation churn was the limiter):
//     kernel dropped below the harness's 40us fill dispatches (>5 TB/s).
// R7: unroll-2 flat: -1.3us (noise-level). R8: unroll-4 neutral => read-path
//     roofline at ~5.2 TB/s (83% of m13 copy ceiling) for the 3-stream read.
// R9: fuse the finalize dispatch away. Single-pass last-block-done reduction:
//     block partial -> threadfence(release) -> atomicAdd(done); last block
//     acquires + reduces 4096 partials + divides. Counter zeroed per
//     iteration by a 4B hipMemsetAsync node (ws is re-poisoned by harness).
//     Predicted: -4..-6us total (one dispatch + launch gap removed).

typedef float  f4_t __attribute__((ext_vector_type(4)));
typedef int    i4_t __attribute__((ext_vector_type(4)));

__device__ __forceinline__ void bce_accum(const f4_t& x, const f4_t& t,
                                          const i4_t& m, float& sum, float& cnt)
{
    #pragma unroll
    for (int k = 0; k < 4; ++k) {
        float xx  = x[k];
        float sp  = __logf(1.0f + __expf(-fabsf(xx)));   // softplus(-|x|)
        float bce = fmaxf(xx, 0.0f) - xx * t[k] + sp;
        float mf  = (float)m[k];   // mask is 0/1
        sum += bce * mf;
        cnt += mf;
    }
}

// Single-pass fused kernel: streaming partials + last-block finalize.
__global__ __launch_bounds__(256) void bce_flat4_fused_kernel(
    const f4_t* __restrict__ logits,
    const f4_t* __restrict__ targets,
    const i4_t* __restrict__ mask,
    float2* __restrict__ partials,      // one float2 {sum, count} per block
    unsigned int* __restrict__ done,    // zeroed by memset node each launch
    float* __restrict__ out,
    int n4)
{
    int i0 = blockIdx.x * 1024 + threadIdx.x;  // 4 coalesced triples/thread
    int i1 = i0 + 256;
    int i2 = i0 + 512;
    int i3 = i0 + 768;

    float sum = 0.0f;
    float cnt = 0.0f;

    if (i3 < n4) {
        // 12 independent NT loads issued before any consumption.
        f4_t x0 = __builtin_nontemporal_load(&logits[i0]);
        f4_t x1 = __builtin_nontemporal_load(&logits[i1]);
        f4_t x2 = __builtin_nontemporal_load(&logits[i2]);
        f4_t x3 = __builtin_nontemporal_load(&logits[i3]);
        f4_t t0 = __builtin_nontemporal_load(&targets[i0]);
        f4_t t1 = __builtin_nontemporal_load(&targets[i1]);
        f4_t t2 = __builtin_nontemporal_load(&targets[i2]);
        f4_t t3 = __builtin_nontemporal_load(&targets[i3]);
        i4_t m0 = __builtin_nontemporal_load(&mask[i0]);
        i4_t m1 = __builtin_nontemporal_load(&mask[i1]);
        i4_t m2 = __builtin_nontemporal_load(&mask[i2]);
        i4_t m3 = __builtin_nontemporal_load(&mask[i3]);

        bce_accum(x0, t0, m0, sum, cnt);
        bce_accum(x1, t1, m1, sum, cnt);
        bce_accum(x2, t2, m2, sum, cnt);
        bce_accum(x3, t3, m3, sum, cnt);
    } else {
        // Tail (not taken for n4 = 4096*1024, kept for generality).
        for (int i = i0; i < n4; i += 256) {
            f4_t x = __builtin_nontemporal_load(&logits[i]);
            f4_t t = __builtin_nontemporal_load(&targets[i]);
            i4_t m = __builtin_nontemporal_load(&mask[i]);
            bce_accum(x, t, m, sum, cnt);
        }
    }

    // Wave-64 shuffle reduction
    #pragma unroll
    for (int off = 32; off > 0; off >>= 1) {
        sum += __shfl_down(sum, off, 64);
        cnt += __shfl_down(cnt, off, 64);
    }

    // Cross-wave reduction via LDS (4 waves per 256-thread block)
    __shared__ float2 wsum[4];
    __shared__ int s_last;
    int lane = threadIdx.x & 63;
    int wid  = threadIdx.x >> 6;
    if (lane == 0) wsum[wid] = make_float2(sum, cnt);
    __syncthreads();
    if (threadIdx.x == 0) {
        float s = 0.0f, c = 0.0f;
        #pragma unroll
        for (int w = 0; w < 4; ++w) { s += wsum[w].x; c += wsum[w].y; }
        partials[blockIdx.x] = make_float2(s, c);
        __threadfence();                              // release partial
        unsigned int old = atomicAdd(done, 1u);       // device-scope
        s_last = (old == (unsigned int)gridDim.x - 1u) ? 1 : 0;
    }
    __syncthreads();

    if (s_last) {
        // All other blocks' partials are globally visible (their release
        // fence ordered the store before the counter bump we observed).
        __threadfence();                              // acquire
        const volatile float* vp = (const volatile float*)partials;
        float fs = 0.0f, fc = 0.0f;
        for (int i = threadIdx.x; i < (int)gridDim.x; i += 256) {
            fs += vp[2 * i];
            fc += vp[2 * i + 1];
        }
        #pragma unroll
        for (int off = 32; off > 0; off >>= 1) {
            fs += __shfl_down(fs, off, 64);
            fc += __shfl_down(fc, off, 64);
        }
        if (lane == 0) wsum[wid] = make_float2(fs, fc);
        __syncthreads();
        if (threadIdx.x == 0) {
            float s = 0.0f, c = 0.0f;
            #pragma unroll
            for (int w = 0; w < 4; ++w) { s += wsum[w].x; c += wsum[w].y; }
            out[0] = s / fmaxf(c, 1.0f);
        }
    }
}

// Fallback (ws too small for one partial per block): grid-stride version.
__global__ __launch_bounds__(256) void bce_strided_partial_kernel(
    const f4_t* __restrict__ logits,
    const f4_t* __restrict__ targets,
    const i4_t* __restrict__ mask,
    float2* __restrict__ partials,
    int n4)
{
    int tid    = blockIdx.x * blockDim.x + threadIdx.x;
    int stride = gridDim.x * blockDim.x;
    float sum = 0.0f, cnt = 0.0f;
    for (int i = tid; i < n4; i += stride) {
        f4_t x = __builtin_nontemporal_load(&logits[i]);
        f4_t t = __builtin_nontemporal_load(&targets[i]);
        i4_t m = __builtin_nontemporal_load(&mask[i]);
        bce_accum(x, t, m, sum, cnt);
    }
    #pragma unroll
    for (int off = 32; off > 0; off >>= 1) {
        sum += __shfl_down(sum, off, 64);
        cnt += __shfl_down(cnt, off, 64);
    }
    __shared__ float2 wsum[4];
    int lane = threadIdx.x & 63;
    int wid  = threadIdx.x >> 6;
    if (lane == 0) wsum[wid] = make_float2(sum, cnt);
    __syncthreads();
    if (threadIdx.x == 0) {
        float s = 0.0f, c = 0.0f;
        #pragma unroll
        for (int w = 0; w < 4; ++w) { s += wsum[w].x; c += wsum[w].y; }
        partials[blockIdx.x] = make_float2(s, c);
    }
}

__global__ __launch_bounds__(1024) void bce_finalize_kernel(
    const float2* __restrict__ partials,
    float* __restrict__ out,
    int nblocks)
{
    float sum = 0.0f, cnt = 0.0f;
    for (int i = threadIdx.x; i < nblocks; i += 1024) {
        float2 p = partials[i];
        sum += p.x;
        cnt += p.y;
    }
    #pragma unroll
    for (int off = 32; off > 0; off >>= 1) {
        sum += __shfl_down(sum, off, 64);
        cnt += __shfl_down(cnt, off, 64);
    }
    __shared__ float2 wsum[16];
    int lane = threadIdx.x & 63;
    int wid  = threadIdx.x >> 6;
    if (lane == 0) wsum[wid] = make_float2(sum, cnt);
    __syncthreads();
    if (threadIdx.x == 0) {
        float s = 0.0f, c = 0.0f;
        #pragma unroll
        for (int w = 0; w < 16; ++w) { s += wsum[w].x; c += wsum[w].y; }
        out[0] = s / fmaxf(c, 1.0f);
    }
}

extern "C" void kernel_launch(void* const* d_in, const int* in_sizes, int n_in,
                              void* d_out, int out_size, void* d_ws, size_t ws_size,
                              hipStream_t stream) {
    const f4_t* logits  = (const f4_t*)d_in[0];
    const f4_t* targets = (const f4_t*)d_in[1];
    const i4_t* mask    = (const i4_t*)d_in[2];
    float*  out      = (float*)d_out;
    float2* partials = (float2*)d_ws;

    int n  = in_sizes[0];      // 16*1024*1024
    int n4 = n / 4;            // 4,194,304 float4 groups

    int flat_grid = (n4 + 1023) / 1024;   // 4096: four float4-triples/thread
    size_t need = (size_t)flat_grid * sizeof(float2) + sizeof(unsigned int);

    if (ws_size >= need) {
        // done-counter lives right after the partials array in ws.
        unsigned int* done =
            (unsigned int*)((char*)d_ws + (size_t)flat_grid * sizeof(float2));
        // ws is re-poisoned by the harness each iteration: zero the counter
        // in-stream (graph-capturable memset node, 4 bytes).
        hipMemsetAsync(done, 0, sizeof(unsigned int), stream);
        bce_flat4_fused_kernel<<<flat_grid, 256, 0, stream>>>(
            logits, targets, mask, partials, done, out, n4);
    } else {
        int grid = (int)(ws_size / sizeof(float2));
        if (grid > 2048) grid = 2048;
        if (grid < 1) grid = 1;
        bce_strided_partial_kernel<<<grid, 256, 0, stream>>>(
            logits, targets, mask, partials, n4);
        bce_finalize_kernel<<<1, 1024, 0, stream>>>(partials, out, grid);
    }
}

// Round 2
// 174.744 us; speedup vs baseline: 2.1788x; 2.1788x over previous
//
#include <hip/hip_runtime.h>
#include <math.h>

// Masked-mean BCE-with-logits:
//   bce = max(x,0) - x*t + log1p(exp(-|x|)); out = sum(bce*m)/max(sum(m),1)
//
// R1: same-address double atomics serialize -> block partials.
// R2: libm log1pf ~250 VALU inst/elem -> HW __expf/__logf softplus.
// R3-R5: three structures converged ~2.9 TB/s -> looked like a ceiling.
// R6: NONTEMPORAL loads broke it (L2-allocation churn was the limiter):
//     kernel dropped below the harness's 40us fill dispatches (>5 TB/s).
// R7: unroll-2 flat: -1.3us (noise). R8: unroll-4 neutral => read-path
//     roofline at ~5.2 TB/s (83% of m13 copy ceiling) for the 3-stream read.
// R9 FAILED (+205us): single-pass last-block-done fusion. threadfence +
//     same-address device atomic from 4096 blocks serializes at ~50ns/block
//     across the 8 non-coherent L2s (243us kernel @ 5% HBM, 4.8% VALU).
//     Cross-XCD handoff must be paid ONCE (kernel boundary), not per block.
// R10: revert to R8 two-dispatch structure; finalize trimmed to 256 threads
//     with float4 partial loads (launch-overhead-bound anyway).

typedef float  f4_t __attribute__((ext_vector_type(4)));
typedef int    i4_t __attribute__((ext_vector_type(4)));

__device__ __forceinline__ void bce_accum(const f4_t& x, const f4_t& t,
                                          const i4_t& m, float& sum, float& cnt)
{
    #pragma unroll
    for (int k = 0; k < 4; ++k) {
        float xx  = x[k];
        float sp  = __logf(1.0f + __expf(-fabsf(xx)));   // softplus(-|x|)
        float bce = fmaxf(xx, 0.0f) - xx * t[k] + sp;
        float mf  = (float)m[k];   // mask is 0/1
        sum += bce * mf;
        cnt += mf;
    }
}

__global__ __launch_bounds__(256) void bce_flat4_partial_kernel(
    const f4_t* __restrict__ logits,
    const f4_t* __restrict__ targets,
    const i4_t* __restrict__ mask,
    float2* __restrict__ partials,   // one float2 {sum, count} per block
    int n4)
{
    int i0 = blockIdx.x * 1024 + threadIdx.x;  // 4 coalesced triples/thread
    int i1 = i0 + 256;
    int i2 = i0 + 512;
    int i3 = i0 + 768;

    float sum = 0.0f;
    float cnt = 0.0f;

    if (i3 < n4) {
        // 12 independent NT loads issued before any consumption.
        f4_t x0 = __builtin_nontemporal_load(&logits[i0]);
        f4_t x1 = __builtin_nontemporal_load(&logits[i1]);
        f4_t x2 = __builtin_nontemporal_load(&logits[i2]);
        f4_t x3 = __builtin_nontemporal_load(&logits[i3]);
        f4_t t0 = __builtin_nontemporal_load(&targets[i0]);
        f4_t t1 = __builtin_nontemporal_load(&targets[i1]);
        f4_t t2 = __builtin_nontemporal_load(&targets[i2]);
        f4_t t3 = __builtin_nontemporal_load(&targets[i3]);
        i4_t m0 = __builtin_nontemporal_load(&mask[i0]);
        i4_t m1 = __builtin_nontemporal_load(&mask[i1]);
        i4_t m2 = __builtin_nontemporal_load(&mask[i2]);
        i4_t m3 = __builtin_nontemporal_load(&mask[i3]);

        bce_accum(x0, t0, m0, sum, cnt);
        bce_accum(x1, t1, m1, sum, cnt);
        bce_accum(x2, t2, m2, sum, cnt);
        bce_accum(x3, t3, m3, sum, cnt);
    } else {
        // Tail (not taken for n4 = 4096*1024, kept for generality).
        for (int i = i0; i < n4; i += 256) {
            f4_t x = __builtin_nontemporal_load(&logits[i]);
            f4_t t = __builtin_nontemporal_load(&targets[i]);
            i4_t m = __builtin_nontemporal_load(&mask[i]);
            bce_accum(x, t, m, sum, cnt);
        }
    }

    // Wave-64 shuffle reduction
    #pragma unroll
    for (int off = 32; off > 0; off >>= 1) {
        sum += __shfl_down(sum, off, 64);
        cnt += __shfl_down(cnt, off, 64);
    }

    // Cross-wave reduction via LDS (4 waves per 256-thread block)
    __shared__ float2 wsum[4];
    int lane = threadIdx.x & 63;
    int wid  = threadIdx.x >> 6;
    if (lane == 0) wsum[wid] = make_float2(sum, cnt);
    __syncthreads();
    if (threadIdx.x == 0) {
        float s = 0.0f, c = 0.0f;
        #pragma unroll
        for (int w = 0; w < 4; ++w) { s += wsum[w].x; c += wsum[w].y; }
        partials[blockIdx.x] = make_float2(s, c);
    }
}

// Fallback (ws too small for one partial per block): grid-stride version.
__global__ __launch_bounds__(256) void bce_strided_partial_kernel(
    const f4_t* __restrict__ logits,
    const f4_t* __restrict__ targets,
    const i4_t* __restrict__ mask,
    float2* __restrict__ partials,
    int n4)
{
    int tid    = blockIdx.x * blockDim.x + threadIdx.x;
    int stride = gridDim.x * blockDim.x;
    float sum = 0.0f, cnt = 0.0f;
    for (int i = tid; i < n4; i += stride) {
        f4_t x = __builtin_nontemporal_load(&logits[i]);
        f4_t t = __builtin_nontemporal_load(&targets[i]);
        i4_t m = __builtin_nontemporal_load(&mask[i]);
        bce_accum(x, t, m, sum, cnt);
    }
    #pragma unroll
    for (int off = 32; off > 0; off >>= 1) {
        sum += __shfl_down(sum, off, 64);
        cnt += __shfl_down(cnt, off, 64);
    }
    __shared__ float2 wsum[4];
    int lane = threadIdx.x & 63;
    int wid  = threadIdx.x >> 6;
    if (lane == 0) wsum[wid] = make_float2(sum, cnt);
    __syncthreads();
    if (threadIdx.x == 0) {
        float s = 0.0f, c = 0.0f;
        #pragma unroll
        for (int w = 0; w < 4; ++w) { s += wsum[w].x; c += wsum[w].y; }
        partials[blockIdx.x] = make_float2(s, c);
    }
}

// Finalize: launch-overhead-bound; 256 threads, float4 loads (2 partials/ld).
__global__ __launch_bounds__(256) void bce_finalize_kernel(
    const float2* __restrict__ partials,
    float* __restrict__ out,
    int nblocks)
{
    float sum = 0.0f, cnt = 0.0f;
    if ((nblocks & 1) == 0) {
        const f4_t* p4 = (const f4_t*)partials;   // {s0,c0,s1,c1}
        int n2 = nblocks >> 1;
        for (int i = threadIdx.x; i < n2; i += 256) {
            f4_t p = p4[i];
            sum += p[0] + p[2];
            cnt += p[1] + p[3];
        }
    } else {
        for (int i = threadIdx.x; i < nblocks; i += 256) {
            float2 p = partials[i];
            sum += p.x;
            cnt += p.y;
        }
    }
    #pragma unroll
    for (int off = 32; off > 0; off >>= 1) {
        sum += __shfl_down(sum, off, 64);
        cnt += __shfl_down(cnt, off, 64);
    }
    __shared__ float2 wsum[4];
    int lane = threadIdx.x & 63;
    int wid  = threadIdx.x >> 6;
    if (lane == 0) wsum[wid] = make_float2(sum, cnt);
    __syncthreads();
    if (threadIdx.x == 0) {
        float s = 0.0f, c = 0.0f;
        #pragma unroll
        for (int w = 0; w < 4; ++w) { s += wsum[w].x; c += wsum[w].y; }
        out[0] = s / fmaxf(c, 1.0f);
    }
}

extern "C" void kernel_launch(void* const* d_in, const int* in_sizes, int n_in,
                              void* d_out, int out_size, void* d_ws, size_t ws_size,
                              hipStream_t stream) {
    const f4_t* logits  = (const f4_t*)d_in[0];
    const f4_t* targets = (const f4_t*)d_in[1];
    const i4_t* mask    = (const i4_t*)d_in[2];
    float*  out      = (float*)d_out;
    float2* partials = (float2*)d_ws;

    int n  = in_sizes[0];      // 16*1024*1024
    int n4 = n / 4;            // 4,194,304 float4 groups

    int flat_grid = (n4 + 1023) / 1024;   // 4096: four float4-triples/thread
    size_t need = (size_t)flat_grid * sizeof(float2);

    if (ws_size >= need) {
        bce_flat4_partial_kernel<<<flat_grid, 256, 0, stream>>>(
            logits, targets, mask, partials, n4);
        bce_finalize_kernel<<<1, 256, 0, stream>>>(partials, out, flat_grid);
    } else {
        int grid = (int)(ws_size / sizeof(float2));
        if (grid > 2048) grid = 2048;
        if (grid < 1) grid = 1;
        bce_strided_partial_kernel<<<grid, 256, 0, stream>>>(
            logits, targets, mask, partials, n4);
        bce_finalize_kernel<<<1, 256, 0, stream>>>(partials, out, grid);
    }
}